// Round 6
// baseline (942.028 us; speedup 1.0000x reference)
//
#include <hip/hip_runtime.h>
#include <hip/hip_bf16.h>

// GraphConvNet: x:[8,2048,32] f32, A0/A1/A2:[8,2048,2048] f32 row-normalized,
// W:[64,224], b/gamma/beta:[64].
// nconv: out[n,w,l] = sum_v A[n,v,w] * x[n,v,l]
// feat = concat([x, x1_0, x2_0, x1_1, x2_1, x1_2, x2_2])  (224 ch)
// h = feat @ W^T + b ; BN over (n,v) per channel; out f32 [8,2048,64]
//
// Fused persistent kernel: each wave streams its A-quarter-tile ONCE,
// retains bf16 MFMA B-fragments in 128 VGPRs, grid-syncs (DIY barrier,
// 512 blocks = exactly 2/CU co-resident), then computes hop2 from the
// retained fragments. A read once per chain: 402 MB total vs 804 MB.

#define V    2048
#define NB   8
#define CIN  32
#define COUT 64
#define CTOT 224

typedef __attribute__((ext_vector_type(8))) short bf16x8;
typedef __attribute__((ext_vector_type(16))) float f32x16;

static __device__ __forceinline__ short f2bf(float f) {
  __hip_bfloat16 h = __float2bfloat16(f);  // RNE
  return *reinterpret_cast<short*>(&h);
}

// ---------------------------------------------------------------------------
// Block: (n, 32-w strip); 4 waves = K-quarters (512 v). Per chain:
// Phase A: stream A f32 (reg-ring 4, vmcnt(48)), cvt->retain bfr[32], MFMA
//          vs x fragments -> x1 strip. Grid barrier.
// Phase B: stream x1 (reg-ring 4, vmcnt(24)), MFMA vs retained bfr -> x2.
// k-map (same bijection both operands): v = v0 + 16*chunk + 8g + j.
// ---------------------------------------------------------------------------
__global__ __launch_bounds__(256, 2) void nconv_fused_kernel(
    const float* __restrict__ A0g, const float* __restrict__ A1g,
    const float* __restrict__ A2g, const float* __restrict__ Xg,
    float* __restrict__ x1a, float* __restrict__ x2a,
    float* __restrict__ x1b, float* __restrict__ x2b,
    float* __restrict__ x1c, float* __restrict__ x2c,
    unsigned* __restrict__ cnt) {
  __shared__ float Lred[4][32][33];  // ~17 KB

  const int bid  = blockIdx.x;    // 512 blocks = 2/CU (guaranteed resident)
  const int n    = bid >> 6;
  const int ws   = (bid & 63) * 32;
  const int t    = threadIdx.x;
  const int q    = t >> 6;        // wave id = K quarter
  const int lane = t & 63;
  const int g    = lane >> 5;
  const int mn   = lane & 31;     // m (=l) for A-op, n (=w) for B-op

  const float* __restrict__ Xp =
      Xg + (size_t)n * V * CIN + (q * 512 + 8 * g) * CIN + mn;

  f32x16 acc;
  auto zero_acc = [&]() {
#pragma unroll
    for (int r = 0; r < 16; ++r) acc[r] = 0.f;
  };

  auto reduce_store = [&](float* __restrict__ Out) {
    __syncthreads();
#pragma unroll
    for (int r = 0; r < 16; ++r)
      Lred[q][(r & 3) + 8 * (r >> 2) + 4 * g][mn] = acc[r];
    __syncthreads();
    const int w = t >> 3, l4 = t & 7;
    float4 o;
    float* op = &o.x;
#pragma unroll
    for (int i = 0; i < 4; ++i)
      op[i] = Lred[0][l4 * 4 + i][w] + Lred[1][l4 * 4 + i][w] +
              Lred[2][l4 * 4 + i][w] + Lred[3][l4 * 4 + i][w];
    *(float4*)(Out + ((size_t)n * V + ws + w) * CIN + l4 * 4) = o;
  };

  auto grid_sync = [&](unsigned target) {
    __threadfence();   // drain own stores to coherence point (wb L2)
    __syncthreads();   // all threads fenced before arrival
    if (t == 0) {
      __hip_atomic_fetch_add(cnt, 1u, __ATOMIC_RELEASE,
                             __HIP_MEMORY_SCOPE_AGENT);
      while (__hip_atomic_load(cnt, __ATOMIC_ACQUIRE,
                               __HIP_MEMORY_SCOPE_AGENT) < target)
        __builtin_amdgcn_s_sleep(32);
    }
    __syncthreads();
    __threadfence();   // acquire: invalidate stale cached lines
  };

#define WAITV(N)                                          \
  do {                                                    \
    asm volatile("s_waitcnt vmcnt(" #N ")" ::: "memory"); \
    __builtin_amdgcn_sched_barrier(0);                    \
  } while (0)

#define STAGE_A(S, C)                                              \
  do {                                                             \
    const float* __restrict__ ap_ = Ap + (size_t)(C) * (16 * V);   \
    const float* __restrict__ pp_ = Xp + (C) * (16 * CIN);         \
    _Pragma("unroll") for (int j = 0; j < 8; ++j) {                \
      a##S[j] = ap_[(size_t)j * V];                                \
      p##S[j] = pp_[j * CIN];                                      \
    }                                                              \
  } while (0)

#define KEEP(S, C)                                                   \
  do {                                                               \
    bf16x8 af_;                                                      \
    _Pragma("unroll") for (int j = 0; j < 8; ++j) {                  \
      af_[j] = f2bf(p##S[j]);                                        \
      bfr[C][j] = f2bf(a##S[j]);                                     \
    }                                                                \
    acc = __builtin_amdgcn_mfma_f32_32x32x16_bf16(af_, bfr[C], acc,  \
                                                  0, 0, 0);          \
  } while (0)

#define STAGE_B(S, C)                                              \
  do {                                                             \
    const float* __restrict__ yp_ = Yp + (C) * (16 * CIN);         \
    _Pragma("unroll") for (int j = 0; j < 8; ++j)                  \
      y##S[j] = yp_[j * CIN];                                      \
  } while (0)

#define CONS(S, C)                                                   \
  do {                                                               \
    bf16x8 af_;                                                      \
    _Pragma("unroll") for (int j = 0; j < 8; ++j)                    \
      af_[j] = f2bf(y##S[j]);                                        \
    acc = __builtin_amdgcn_mfma_f32_32x32x16_bf16(af_, bfr[C], acc,  \
                                                  0, 0, 0);          \
  } while (0)

#define PA(SS, CS, SU, CU) STAGE_A(SS, CS); WAITV(48); KEEP(SU, CU)
#define PB(SS, CS, SU, CU) STAGE_B(SS, CS); WAITV(24); CONS(SU, CU)

#pragma unroll 1
  for (int ch = 0; ch < 3; ++ch) {
    const float* __restrict__ Adj = ch == 0 ? A0g : (ch == 1 ? A1g : A2g);
    float* __restrict__ X1 = ch == 0 ? x1a : (ch == 1 ? x1b : x1c);
    float* __restrict__ X2 = ch == 0 ? x2a : (ch == 1 ? x2b : x2c);
    const float* __restrict__ Ap =
        Adj + (size_t)n * V * V + (size_t)(q * 512 + 8 * g) * V + ws + mn;

    bf16x8 bfr[32];  // retained B-operand fragments: 128 VGPRs
    float a0[8], a1[8], a2[8], a3[8];
    float p0[8], p1[8], p2[8], p3[8];

    // -------- Phase A: hop1, retain A fragments --------
    zero_acc();
    STAGE_A(0, 0); STAGE_A(1, 1); STAGE_A(2, 2);
    PA(3, 3, 0, 0);   PA(0, 4, 1, 1);   PA(1, 5, 2, 2);   PA(2, 6, 3, 3);
    PA(3, 7, 0, 4);   PA(0, 8, 1, 5);   PA(1, 9, 2, 6);   PA(2, 10, 3, 7);
    PA(3, 11, 0, 8);  PA(0, 12, 1, 9);  PA(1, 13, 2, 10); PA(2, 14, 3, 11);
    PA(3, 15, 0, 12); PA(0, 16, 1, 13); PA(1, 17, 2, 14); PA(2, 18, 3, 15);
    PA(3, 19, 0, 16); PA(0, 20, 1, 17); PA(1, 21, 2, 18); PA(2, 22, 3, 19);
    PA(3, 23, 0, 20); PA(0, 24, 1, 21); PA(1, 25, 2, 22); PA(2, 26, 3, 23);
    PA(3, 27, 0, 24); PA(0, 28, 1, 25); PA(1, 29, 2, 26); PA(2, 30, 3, 27);
    PA(3, 31, 0, 28);
    WAITV(32); KEEP(1, 29);
    WAITV(16); KEEP(2, 30);
    WAITV(0);  KEEP(3, 31);

    reduce_store(X1);
    grid_sync(512u * (unsigned)(ch + 1));

    // -------- Phase B: hop2 from retained fragments --------
    const float* __restrict__ Yp =
        X1 + (size_t)n * V * CIN + (q * 512 + 8 * g) * CIN + mn;
    float y0[8], y1[8], y2[8], y3[8];
    zero_acc();
    STAGE_B(0, 0); STAGE_B(1, 1); STAGE_B(2, 2);
    PB(3, 3, 0, 0);   PB(0, 4, 1, 1);   PB(1, 5, 2, 2);   PB(2, 6, 3, 3);
    PB(3, 7, 0, 4);   PB(0, 8, 1, 5);   PB(1, 9, 2, 6);   PB(2, 10, 3, 7);
    PB(3, 11, 0, 8);  PB(0, 12, 1, 9);  PB(1, 13, 2, 10); PB(2, 14, 3, 11);
    PB(3, 15, 0, 12); PB(0, 16, 1, 13); PB(1, 17, 2, 14); PB(2, 18, 3, 15);
    PB(3, 19, 0, 16); PB(0, 20, 1, 17); PB(1, 21, 2, 18); PB(2, 22, 3, 19);
    PB(3, 23, 0, 20); PB(0, 24, 1, 21); PB(1, 25, 2, 22); PB(2, 26, 3, 23);
    PB(3, 27, 0, 24); PB(0, 28, 1, 25); PB(1, 29, 2, 26); PB(2, 30, 3, 27);
    PB(3, 31, 0, 28);
    WAITV(16); CONS(1, 29);
    WAITV(8);  CONS(2, 30);
    WAITV(0);  CONS(3, 31);

    reduce_store(X2);
    // no inter-chain sync needed: next chain reads only A(ch+1) and x
  }

#undef WAITV
#undef STAGE_A
#undef KEEP
#undef STAGE_B
#undef CONS
#undef PA
#undef PB
}

// ---------------------------------------------------------------------------
// conv 1x1 + bias + BN batch-stats partials (unchanged, passing).
// ---------------------------------------------------------------------------
__global__ __launch_bounds__(256) void conv_bn_stats_kernel(
    const float* __restrict__ W, const float* __restrict__ bias,
    const float* __restrict__ p0, const float* __restrict__ p1,
    const float* __restrict__ p2, const float* __restrict__ p3,
    const float* __restrict__ p4, const float* __restrict__ p5,
    const float* __restrict__ p6, float* __restrict__ hout,
    float* __restrict__ stats) {
  __shared__ float Wl[COUT * CTOT];
  __shared__ float Fl[64 * CTOT];
  const int t = threadIdx.x;
  const int R0 = blockIdx.x * 64;

#pragma unroll
  for (int s = 0; s < 14; ++s) {
    int fl = t + s * 256;
    int o = fl / 56, c4 = fl % 56;
    float4 wv = *(const float4*)(W + o * CTOT + c4 * 4);
    int c = c4 * 4;
    int csw = c ^ (((o >> 2) & 7) << 2);
    *(float4*)&Wl[o * CTOT + csw] = wv;
  }
  const float* parts[7] = {p0, p1, p2, p3, p4, p5, p6};
#pragma unroll
  for (int p = 0; p < 7; ++p) {
    const float* __restrict__ src = parts[p] + (size_t)R0 * CIN;
#pragma unroll
    for (int s = 0; s < 2; ++s) {
      int fl = t + s * 256;
      int r = fl >> 3, c4 = fl & 7;
      float4 v = *(const float4*)(src + r * CIN + c4 * 4);
      int c = p * 32 + c4 * 4;
      int csw = c ^ (((r >> 2) & 7) << 2);
      *(float4*)&Fl[r * CTOT + csw] = v;
    }
  }
  __syncthreads();

  const int rg = t & 15, og = t >> 4;
  const int r0 = rg * 4, o0 = og * 4;
  float acc[4][4];
#pragma unroll
  for (int i = 0; i < 4; ++i)
#pragma unroll
    for (int j = 0; j < 4; ++j) acc[i][j] = bias[o0 + j];

  const int fsw = (rg & 7) << 2;
  const int wsw = (og & 7) << 2;
  for (int cc = 0; cc < CTOT; cc += 4) {
    float4 f[4], w[4];
#pragma unroll
    for (int i = 0; i < 4; ++i)
      f[i] = *(const float4*)&Fl[(r0 + i) * CTOT + (cc ^ fsw)];
#pragma unroll
    for (int j = 0; j < 4; ++j)
      w[j] = *(const float4*)&Wl[(o0 + j) * CTOT + (cc ^ wsw)];
#pragma unroll
    for (int i = 0; i < 4; ++i)
#pragma unroll
      for (int j = 0; j < 4; ++j)
        acc[i][j] += f[i].x * w[j].x + f[i].y * w[j].y + f[i].z * w[j].z +
                     f[i].w * w[j].w;
  }

#pragma unroll
  for (int i = 0; i < 4; ++i) {
    *(float4*)(hout + (size_t)(R0 + r0 + i) * COUT + o0) =
        make_float4(acc[i][0], acc[i][1], acc[i][2], acc[i][3]);
  }

  __syncthreads();
  float* red = Fl;
#pragma unroll
  for (int j = 0; j < 4; ++j) {
    float s = acc[0][j] + acc[1][j] + acc[2][j] + acc[3][j];
    float qq = acc[0][j] * acc[0][j] + acc[1][j] * acc[1][j] +
               acc[2][j] * acc[2][j] + acc[3][j] * acc[3][j];
    red[(o0 + j) * 16 + rg] = s;
    red[1024 + (o0 + j) * 16 + rg] = qq;
  }
  __syncthreads();
  if (t < 128) {
    int o = t & 63, which = t >> 6;
    const float* b = red + which * 1024 + o * 16;
    float v = 0.f;
#pragma unroll
    for (int k = 0; k < 16; ++k) v += b[k];
    atomicAdd(stats + which * COUT + o, v);
  }
}

// ---------------------------------------------------------------------------
__global__ __launch_bounds__(256) void bn_apply_kernel(
    float* __restrict__ hout, const float* __restrict__ stats,
    const float* __restrict__ gamma, const float* __restrict__ beta) {
  const int i4 = blockIdx.x * 256 + threadIdx.x;
  const int oi = i4 & 15;
  float4 h = ((const float4*)hout)[i4];
  const float4 s = ((const float4*)stats)[oi];
  const float4 q = ((const float4*)(stats + COUT))[oi];
  const float4 g = ((const float4*)gamma)[oi];
  const float4 bb = ((const float4*)beta)[oi];
  const float inv = 1.f / 16384.f;
  float m, vv, rs;
  m = s.x * inv; vv = q.x * inv - m * m; rs = rsqrtf(vv + 1e-5f);
  h.x = (h.x - m) * rs * g.x + bb.x;
  m = s.y * inv; vv = q.y * inv - m * m; rs = rsqrtf(vv + 1e-5f);
  h.y = (h.y - m) * rs * g.y + bb.y;
  m = s.z * inv; vv = q.z * inv - m * m; rs = rsqrtf(vv + 1e-5f);
  h.z = (h.z - m) * rs * g.z + bb.z;
  m = s.w * inv; vv = q.w * inv - m * m; rs = rsqrtf(vv + 1e-5f);
  h.w = (h.w - m) * rs * g.w + bb.w;
  ((float4*)hout)[i4] = h;
}

// ---------------------------------------------------------------------------
extern "C" void kernel_launch(void* const* d_in, const int* in_sizes, int n_in,
                              void* d_out, int out_size, void* d_ws,
                              size_t ws_size, hipStream_t stream) {
  const float* x     = (const float*)d_in[0];
  const float* A0    = (const float*)d_in[1];
  const float* A1    = (const float*)d_in[2];
  const float* A2    = (const float*)d_in[3];
  const float* W     = (const float*)d_in[4];
  const float* b     = (const float*)d_in[5];
  const float* gamma = (const float*)d_in[6];
  const float* beta  = (const float*)d_in[7];
  float* out = (float*)d_out;

  char* ws = (char*)d_ws;
  float* stats = (float*)ws;                    // 2*64 floats
  unsigned* cnt = (unsigned*)(ws + 2048);       // grid-barrier counter
  const size_t BUF = (size_t)NB * V * CIN;      // 524288 floats (2 MB)
  float* x1_0 = (float*)(ws + 4096);
  float* x2_0 = x1_0 + BUF;
  float* x1_1 = x2_0 + BUF;
  float* x2_1 = x1_1 + BUF;
  float* x1_2 = x2_1 + BUF;
  float* x2_2 = x1_2 + BUF;

  hipMemsetAsync(ws, 0, 4096, stream);  // stats + barrier counter

  nconv_fused_kernel<<<dim3(512), dim3(256), 0, stream>>>(
      A0, A1, A2, x, x1_0, x2_0, x1_1, x2_1, x1_2, x2_2, cnt);

  conv_bn_stats_kernel<<<dim3(256), dim3(256), 0, stream>>>(
      W, b, x, x1_0, x2_0, x1_1, x2_1, x1_2, x2_2, out, stats);
  bn_apply_kernel<<<dim3(1024), dim3(256), 0, stream>>>(out, stats, gamma,
                                                        beta);
}

// Round 7
// 212.236 us; speedup vs baseline: 4.4386x; 4.4386x over previous
//
#include <hip/hip_runtime.h>
#include <hip/hip_bf16.h>

// GraphConvNet: x:[8,2048,32] f32, A0/A1/A2:[8,2048,2048] f32 row-normalized,
// W:[64,224], b/gamma/beta:[64].
// nconv: out[n,w,l] = sum_v A[n,v,w] * x[n,v,l]
// feat = concat([x, x1_0, x2_0, x1_1, x2_1, x1_2, x2_2])  (224 ch)
// h = feat @ W^T + b ; BN over (n,v) per channel; out f32 [8,2048,64]

#define V    2048
#define NB   8
#define CIN  32
#define COUT 64
#define CTOT 224

typedef __attribute__((ext_vector_type(8))) short bf16x8;
typedef __attribute__((ext_vector_type(16))) float f32x16;

static __device__ __forceinline__ short f2bf(float f) {
  __hip_bfloat16 h = __float2bfloat16(f);  // RNE
  return *reinterpret_cast<short*>(&h);
}

static __device__ __forceinline__ void gll16(const float* g, float* l) {
  // async global->LDS, 16B/lane; LDS dst = wave-uniform base + lane*16
  __builtin_amdgcn_global_load_lds(
      (const __attribute__((address_space(1))) void*)g,
      (__attribute__((address_space(3))) void*)l, 16, 0, 0);
}

// ---------------------------------------------------------------------------
// nconv via MFMA 32x32x16 bf16, async-LDS pipelined, barrier-free main loop.
// Block: 512 thr = 8 waves, each owns a K-eighth (256 v = 16 chunks of 16v)
// of one (n, 32-w strip). Grid 512 -> 2 blocks/CU, 16 waves/CU (4/SIMD):
// TLP hides the per-chunk LDS-latency chain that capped the 4-wave version.
// LDS 80KB: per wave A ring-3 (2KB slots) + X ring-2. Per iter: stage X(i+1),
// A(i+2), s_waitcnt vmcnt(6)  [audit: retires A(i),X(i); keeps
// A(i+1),A(i+2),X(i+1) in flight], then 16 ds_read + cvt + 1 MFMA.
// k-slot map (same bijection both operands => correct): v = 16c + 8g + j.
// ---------------------------------------------------------------------------
__global__ __launch_bounds__(512, 4) void nconv_mfma_kernel(
    const float* __restrict__ Adj, const float* __restrict__ Xin,
    float* __restrict__ Xout) {
  __shared__ float SA[8][3][16][32];  // 48 KB
  __shared__ float SX[8][2][16][32];  // 32 KB

  const int bid  = blockIdx.x;    // 512 blocks
  const int n    = bid >> 6;
  const int ws   = (bid & 63) * 32;
  const int t    = threadIdx.x;
  const int wq   = t >> 6;        // wave id = K eighth
  const int lane = t & 63;
  const int g    = lane >> 5;
  const int mn   = lane & 31;     // m (=l) for A-op, n (=w) for B-op

  const float* __restrict__ Asrc = Adj + (size_t)n * V * V +
                                   (size_t)(wq * 256) * V + ws +
                                   (size_t)(lane >> 3) * V + (lane & 7) * 4;
  const float* __restrict__ Xsrc =
      Xin + (size_t)n * V * CIN + wq * 256 * CIN + lane * 4;

  auto stage_a = [&](int slot, int c) {
    const float* a = Asrc + (size_t)c * (16 * V);
    gll16(a, &SA[wq][slot][0][0]);
    gll16(a + 8 * V, &SA[wq][slot][8][0]);
  };
  auto stage_x = [&](int slot, int c) {
    const float* x = Xsrc + c * (16 * CIN);
    gll16(x, &SX[wq][slot][0][0]);
    gll16(x + 256, &SX[wq][slot][8][0]);
  };

  f32x16 acc;
#pragma unroll
  for (int r = 0; r < 16; ++r) acc[r] = 0.f;

  auto compute = [&](int sa, int sx) {
    float a8[8], x8[8];
#pragma unroll
    for (int j = 0; j < 8; ++j) {
      a8[j] = SA[wq][sa][8 * g + j][mn];   // Adj[v][w] -> B operand
      x8[j] = SX[wq][sx][8 * g + j][mn];   // X[v][l]   -> A operand (X^T)
    }
    bf16x8 aop, bop;
#pragma unroll
    for (int j = 0; j < 8; ++j) {
      aop[j] = f2bf(x8[j]);
      bop[j] = f2bf(a8[j]);
    }
    acc = __builtin_amdgcn_mfma_f32_32x32x16_bf16(aop, bop, acc, 0, 0, 0);
  };

#define WAITV(N)                                          \
  do {                                                    \
    asm volatile("s_waitcnt vmcnt(" #N ")" ::: "memory"); \
    __builtin_amdgcn_sched_barrier(0);                    \
  } while (0)

  // prologue (iteration order preserved: A0, X0, A1)
  stage_a(0, 0);
  stage_x(0, 0);
  stage_a(1, 1);

  int ca = 0, cx = 0;
#pragma unroll 1
  for (int i = 0; i < 14; ++i) {
    stage_x(cx ^ 1, i + 1);              // X(i+1), slot (i+1)&1
    const int as = (ca == 0) ? 2 : ca - 1;
    stage_a(as, i + 2);                  // A(i+2), slot (i+2)%3
    WAITV(6);                            // A(i), X(i) resident
    compute(ca, cx);
    ca = (ca == 2) ? 0 : ca + 1;
    cx ^= 1;
  }
  // i = 14
  stage_x(cx ^ 1, 15);
  WAITV(4);
  compute(ca, cx);
  ca = (ca == 2) ? 0 : ca + 1;
  cx ^= 1;
  // i = 15
  WAITV(0);
  compute(ca, cx);

#undef WAITV

  // ---- cross-wave K reduce (overlay staging LDS) ----
  __syncthreads();
  float(*Lred)[32][33] = reinterpret_cast<float(*)[32][33]>(&SA[0][0][0][0]);
#pragma unroll
  for (int r = 0; r < 16; ++r) {
    // C^T[l][w]: row l = (r&3)+8*(r>>2)+4*g, col w = mn
    Lred[wq][(r & 3) + 8 * (r >> 2) + 4 * g][mn] = acc[r];
  }
  __syncthreads();
  // 512 threads, 1024 outputs: 2 per thread
  const int w  = t >> 4;
  const int l0 = (t & 15) * 2;
  float2 o;
  o.x = 0.f;
  o.y = 0.f;
#pragma unroll
  for (int k = 0; k < 8; ++k) {
    o.x += Lred[k][l0][w];
    o.y += Lred[k][l0 + 1][w];
  }
  *(float2*)(Xout + ((size_t)n * V + ws + w) * CIN + l0) = o;
}

// ---------------------------------------------------------------------------
// conv 1x1 + bias + BN batch-stats partials (unchanged, passing).
// ---------------------------------------------------------------------------
__global__ __launch_bounds__(256) void conv_bn_stats_kernel(
    const float* __restrict__ W, const float* __restrict__ bias,
    const float* __restrict__ p0, const float* __restrict__ p1,
    const float* __restrict__ p2, const float* __restrict__ p3,
    const float* __restrict__ p4, const float* __restrict__ p5,
    const float* __restrict__ p6, float* __restrict__ hout,
    float* __restrict__ stats) {
  __shared__ float Wl[COUT * CTOT];
  __shared__ float Fl[64 * CTOT];
  const int t = threadIdx.x;
  const int R0 = blockIdx.x * 64;

#pragma unroll
  for (int s = 0; s < 14; ++s) {
    int fl = t + s * 256;
    int o = fl / 56, c4 = fl % 56;
    float4 wv = *(const float4*)(W + o * CTOT + c4 * 4);
    int c = c4 * 4;
    int csw = c ^ (((o >> 2) & 7) << 2);
    *(float4*)&Wl[o * CTOT + csw] = wv;
  }
  const float* parts[7] = {p0, p1, p2, p3, p4, p5, p6};
#pragma unroll
  for (int p = 0; p < 7; ++p) {
    const float* __restrict__ src = parts[p] + (size_t)R0 * CIN;
#pragma unroll
    for (int s = 0; s < 2; ++s) {
      int fl = t + s * 256;
      int r = fl >> 3, c4 = fl & 7;
      float4 v = *(const float4*)(src + r * CIN + c4 * 4);
      int c = p * 32 + c4 * 4;
      int csw = c ^ (((r >> 2) & 7) << 2);
      *(float4*)&Fl[r * CTOT + csw] = v;
    }
  }
  __syncthreads();

  const int rg = t & 15, og = t >> 4;
  const int r0 = rg * 4, o0 = og * 4;
  float acc[4][4];
#pragma unroll
  for (int i = 0; i < 4; ++i)
#pragma unroll
    for (int j = 0; j < 4; ++j) acc[i][j] = bias[o0 + j];

  const int fsw = (rg & 7) << 2;
  const int wsw = (og & 7) << 2;
  for (int cc = 0; cc < CTOT; cc += 4) {
    float4 f[4], w[4];
#pragma unroll
    for (int i = 0; i < 4; ++i)
      f[i] = *(const float4*)&Fl[(r0 + i) * CTOT + (cc ^ fsw)];
#pragma unroll
    for (int j = 0; j < 4; ++j)
      w[j] = *(const float4*)&Wl[(o0 + j) * CTOT + (cc ^ wsw)];
#pragma unroll
    for (int i = 0; i < 4; ++i)
#pragma unroll
      for (int j = 0; j < 4; ++j)
        acc[i][j] += f[i].x * w[j].x + f[i].y * w[j].y + f[i].z * w[j].z +
                     f[i].w * w[j].w;
  }

#pragma unroll
  for (int i = 0; i < 4; ++i) {
    *(float4*)(hout + (size_t)(R0 + r0 + i) * COUT + o0) =
        make_float4(acc[i][0], acc[i][1], acc[i][2], acc[i][3]);
  }

  __syncthreads();
  float* red = Fl;
#pragma unroll
  for (int j = 0; j < 4; ++j) {
    float s = acc[0][j] + acc[1][j] + acc[2][j] + acc[3][j];
    float qq = acc[0][j] * acc[0][j] + acc[1][j] * acc[1][j] +
               acc[2][j] * acc[2][j] + acc[3][j] * acc[3][j];
    red[(o0 + j) * 16 + rg] = s;
    red[1024 + (o0 + j) * 16 + rg] = qq;
  }
  __syncthreads();
  if (t < 128) {
    int o = t & 63, which = t >> 6;
    const float* b = red + which * 1024 + o * 16;
    float v = 0.f;
#pragma unroll
    for (int k = 0; k < 16; ++k) v += b[k];
    atomicAdd(stats + which * COUT + o, v);
  }
}

// ---------------------------------------------------------------------------
__global__ __launch_bounds__(256) void bn_apply_kernel(
    float* __restrict__ hout, const float* __restrict__ stats,
    const float* __restrict__ gamma, const float* __restrict__ beta) {
  const int i4 = blockIdx.x * 256 + threadIdx.x;
  const int oi = i4 & 15;
  float4 h = ((const float4*)hout)[i4];
  const float4 s = ((const float4*)stats)[oi];
  const float4 q = ((const float4*)(stats + COUT))[oi];
  const float4 g = ((const float4*)gamma)[oi];
  const float4 bb = ((const float4*)beta)[oi];
  const float inv = 1.f / 16384.f;
  float m, vv, rs;
  m = s.x * inv; vv = q.x * inv - m * m; rs = rsqrtf(vv + 1e-5f);
  h.x = (h.x - m) * rs * g.x + bb.x;
  m = s.y * inv; vv = q.y * inv - m * m; rs = rsqrtf(vv + 1e-5f);
  h.y = (h.y - m) * rs * g.y + bb.y;
  m = s.z * inv; vv = q.z * inv - m * m; rs = rsqrtf(vv + 1e-5f);
  h.z = (h.z - m) * rs * g.z + bb.z;
  m = s.w * inv; vv = q.w * inv - m * m; rs = rsqrtf(vv + 1e-5f);
  h.w = (h.w - m) * rs * g.w + bb.w;
  ((float4*)hout)[i4] = h;
}

// ---------------------------------------------------------------------------
extern "C" void kernel_launch(void* const* d_in, const int* in_sizes, int n_in,
                              void* d_out, int out_size, void* d_ws,
                              size_t ws_size, hipStream_t stream) {
  const float* x     = (const float*)d_in[0];
  const float* A0    = (const float*)d_in[1];
  const float* A1    = (const float*)d_in[2];
  const float* A2    = (const float*)d_in[3];
  const float* W     = (const float*)d_in[4];
  const float* b     = (const float*)d_in[5];
  const float* gamma = (const float*)d_in[6];
  const float* beta  = (const float*)d_in[7];
  float* out = (float*)d_out;

  char* ws = (char*)d_ws;
  float* stats = (float*)ws;
  const size_t BUF = (size_t)NB * V * CIN;  // 524288 floats
  float* x1_0 = (float*)(ws + 4096);
  float* x2_0 = x1_0 + BUF;
  float* x1_1 = x2_0 + BUF;
  float* x2_1 = x1_1 + BUF;
  float* x1_2 = x2_1 + BUF;
  float* x2_2 = x1_2 + BUF;

  hipMemsetAsync(stats, 0, 2 * COUT * sizeof(float), stream);

  dim3 g(512), blk(512);
  // per-A pairs so hop2 re-reads A from Infinity Cache (134 MB < 256 MB L3)
  nconv_mfma_kernel<<<g, blk, 0, stream>>>(A0, x, x1_0);
  nconv_mfma_kernel<<<g, blk, 0, stream>>>(A0, x1_0, x2_0);
  nconv_mfma_kernel<<<g, blk, 0, stream>>>(A1, x, x1_1);
  nconv_mfma_kernel<<<g, blk, 0, stream>>>(A1, x1_1, x2_1);
  nconv_mfma_kernel<<<g, blk, 0, stream>>>(A2, x, x1_2);
  nconv_mfma_kernel<<<g, blk, 0, stream>>>(A2, x1_2, x2_2);

  conv_bn_stats_kernel<<<dim3(256), dim3(256), 0, stream>>>(
      W, b, x, x1_0, x2_0, x1_1, x2_1, x1_2, x2_2, out, stats);
  bn_apply_kernel<<<dim3(1024), dim3(256), 0, stream>>>(out, stats, gamma,
                                                        beta);
}